// Round 5
// baseline (472.765 us; speedup 1.0000x reference)
//
#include <hip/hip_runtime.h>

#define OUT_W 320
#define OUT_H 240
#define NPIX (OUT_W * OUT_H)
#define S_IN 128
#define SLICE (S_IN * S_IN)
#define VOLC (S_IN * S_IN * S_IN)
#define ZSEG 8                  // waves per block, each owns 32 z-samples
#define NBLK (NPIX / 64)        // 1200 blocks
#define CPX  (NBLK / 8)         // 150 blocks per XCD (1200 % 8 == 0 -> bijective)

// One block = 64 pixels (one image-row span, y uniform) x 8 z-segment waves.
// Slice schedule is EXACT: k(z) = (z-1)>>1 for the 128->256 resample, so the
// z-loop is a static unrolled pipeline of {16-tap gather, 2 composite steps}.
// Segment results (T, wsum, accRGB) combine associatively in LDS.
__global__ __launch_bounds__(512, 6) void raycast_kernel(const float* __restrict__ vol,
                                                         float* __restrict__ out) {
    const int lane = threadIdx.x & 63;
    const int seg  = threadIdx.x >> 6;                               // 0..7
    const int o    = (blockIdx.x & 7) * CPX + (blockIdx.x >> 3);     // XCD-contiguous index
    const int pix  = o * 64 + lane;
    const int x = pix % OUT_W;
    const int y = pix / OUT_W;   // uniform within block

    // ---- bilinear (y,x) setup: grid_sample align_corners=False, zero padding ----
    float fx = (float)x * (128.0f / 319.0f) - 0.5f;
    int   ix0 = (int)floorf(fx);
    float wx1 = fx - (float)ix0;
    float wx0 = 1.0f - wx1;
    float wxa = (ix0 >= 0)       ? wx0 : 0.0f;
    float wxb = (ix0 + 1 < S_IN) ? wx1 : 0.0f;
    int   cx0 = max(ix0, 0);
    int   cx1 = min(ix0 + 1, S_IN - 1);

    float fy = (float)y * (128.0f / 239.0f) - 0.5f;
    int   iy0 = (int)floorf(fy);
    float wy1 = fy - (float)iy0;
    float wy0 = 1.0f - wy1;
    float wya = (iy0 >= 0)       ? wy0 : 0.0f;
    float wyb = (iy0 + 1 < S_IN) ? wy1 : 0.0f;
    int   cy0 = max(iy0, 0);
    int   cy1 = min(iy0 + 1, S_IN - 1);

    const float w00 = wya * wxa, w01 = wya * wxb, w10 = wyb * wxa, w11 = wyb * wxb;
    const int o00 = cy0 * S_IN + cx0;
    const int o01 = cy0 * S_IN + cx1;
    const int o10 = cy1 * S_IN + cx0;
    const int o11 = cy1 * S_IN + cx1;

    // bilinear sample of all 4 channels at input slice k (k uniform per wave)
    auto bilin = [&](int k, float s[4]) {
        const float* p = vol + k * SLICE;
#pragma unroll
        for (int c = 0; c < 4; ++c) {
            const float* q = p + c * VOLC;
            s[c] = w00 * q[o00] + w01 * q[o01] + w10 * q[o10] + w11 * q[o11];
        }
    };

    float T = 1.f, wsum = 0.f, a0 = 0.f, a1 = 0.f, a2 = 0.f;

    // one composite step at output z using slices k (S0) and k+1 (S1)
    auto step = [&](int z, int k, const float* S0, const float* S1) {
        float fz  = (float)z * (128.0f / 255.0f) - 0.5f;
        float wz1 = fz - (float)k;           // edge taps carry zeroed DATA, so no weight mask
        float wz0 = 1.0f - wz1;
        float r  = wz0 * S0[0] + wz1 * S1[0];
        float g  = wz0 * S0[1] + wz1 * S1[1];
        float bb = wz0 * S0[2] + wz1 * S1[2];
        float dv = wz0 * S0[3] + wz1 * S1[3];
        float d  = dv * (100.0f / 256.0f);   // DENSITY_FACTOR / RAY_SAMPLES
        T *= (1.0f - d);                      // inclusive cumprod
        float w = d * T;
        wsum += w;
        a0 += w * r; a1 += w * g; a2 += w * bb;
    };

    // ---- z-segment: z in [32*seg, 32*seg+32), slices 16*seg-1 .. 16*seg+16 ----
    const int m0 = 16 * seg - 1;
    const int zb = 32 * seg;
    float A[4], B[4], C[4];
    if (m0 >= 0) bilin(m0, A);
    else { A[0] = A[1] = A[2] = A[3] = 0.f; }   // zero-pad below volume
    bilin(m0 + 1, B);

    step(zb, m0, A, B);                         // lone even step (pair-mate in prev segment)
#pragma unroll
    for (int j = 0; j < 15; ++j) {              // slices m0+2+j <= 127 always valid
        bilin(m0 + 2 + j, C);
        step(zb + 1 + 2 * j, m0 + 1 + j, B, C);
        step(zb + 2 + 2 * j, m0 + 1 + j, B, C);
#pragma unroll
        for (int c = 0; c < 4; ++c) B[c] = C[c];
    }
    if (16 * seg + 16 < S_IN) bilin(16 * seg + 16, C);
    else { C[0] = C[1] = C[2] = C[3] = 0.f; }   // zero-pad above volume (seg 7 only)
    step(zb + 31, 16 * seg + 15, B, C);         // lone odd step (pair-mate in next segment)

    // ---- combine 8 segments per pixel (associative composition) ----
    __shared__ float shT[ZSEG][64], shW[ZSEG][64], sh0[ZSEG][64], sh1[ZSEG][64], sh2[ZSEG][64];
    shT[seg][lane] = T;
    shW[seg][lane] = wsum;
    sh0[seg][lane] = a0;
    sh1[seg][lane] = a1;
    sh2[seg][lane] = a2;
    __syncthreads();

    if (threadIdx.x < 64) {
        float Tg = 1.f, ws = 0.f, r0 = 0.f, r1 = 0.f, r2 = 0.f;
#pragma unroll
        for (int s = 0; s < ZSEG; ++s) {
            r0 += Tg * sh0[s][lane];
            r1 += Tg * sh1[s][lane];
            r2 += Tg * sh2[s][lane];
            ws += Tg * shW[s][lane];
            Tg *= shT[s][lane];
        }
        float alpha = 1.0f - Tg;
        float inv   = alpha / (ws + 1e-8f);
        out[0 * NPIX + pix] = r0 * inv;
        out[1 * NPIX + pix] = r1 * inv;
        out[2 * NPIX + pix] = r2 * inv;
        out[3 * NPIX + pix] = alpha;
    }
}

extern "C" void kernel_launch(void* const* d_in, const int* in_sizes, int n_in,
                              void* d_out, int out_size, void* d_ws, size_t ws_size,
                              hipStream_t stream) {
    (void)in_sizes; (void)n_in; (void)out_size; (void)d_ws; (void)ws_size;
    const float* vol = (const float*)d_in[0];
    float* out = (float*)d_out;
    raycast_kernel<<<NBLK, 512, 0, stream>>>(vol, out);
}